// Round 1
// baseline (487.005 us; speedup 1.0000x reference)
//
#include <hip/hip_runtime.h>
#include <hip/hip_bf16.h>

typedef __attribute__((ext_vector_type(8))) short bf16x8;
typedef __attribute__((ext_vector_type(4))) float f32x4;

#define Bn 8
#define Tn 2048
#define Kn 64
#define Hn 8
#define KSn 5
#define CHn (Kn*Hn)  /* 512 */

__device__ __forceinline__ unsigned short f2bf(float f) {
    unsigned int x = __builtin_bit_cast(unsigned int, f);
    unsigned int r = (x + 0x7fffu + ((x >> 16) & 1u)) >> 16;
    return (unsigned short)r;
}

// ---------------- prep: dtype conversions + weight reformat + scale folding ---------
__global__ void prep_kernel(const float* __restrict__ x,
                            const float* __restrict__ wq, const float* __restrict__ bq,
                            const float* __restrict__ wk, const float* __restrict__ bk,
                            const float* __restrict__ wv,
                            const float* __restrict__ wu,
                            unsigned short* __restrict__ x_b,
                            unsigned short* __restrict__ w2q, unsigned short* __restrict__ w2k,
                            unsigned short* __restrict__ w2v,
                            unsigned short* __restrict__ wu_b,
                            float* __restrict__ bqs, float* __restrict__ bks)
{
    const float inv_scale = 0.35355339059327373f; // 64^-0.25
    const int N0 = Bn*Tn*Kn;          // 1048576
    const int N1 = KSn*CHn*Kn;        // 163840
    const int total = N0 + 3*N1 + CHn*Kn + 2*CHn;
    for (int i = blockIdx.x*blockDim.x + threadIdx.x; i < total; i += gridDim.x*blockDim.x) {
        if (i < N0) { x_b[i] = f2bf(x[i]); continue; }
        int r = i - N0;
        if (r < 3*N1) {
            int conv = r / N1; int rr = r - conv*N1;
            int j = rr / (CHn*Kn); int rc = rr - j*(CHn*Kn);
            int c = rc >> 6; int ic = rc & 63;
            const float* w = (conv==0) ? wq : ((conv==1) ? wk : wv);
            float s = (conv==2) ? 1.0f : inv_scale;
            unsigned short* dst = (conv==0) ? w2q : ((conv==1) ? w2k : w2v);
            dst[rr] = f2bf(w[(c*Kn + ic)*KSn + j] * s);
            continue;
        }
        r -= 3*N1;
        if (r < CHn*Kn) { wu_b[r] = f2bf(wu[r]); continue; }
        r -= CHn*Kn;
        if (r < CHn) { bqs[r] = bq[r]*inv_scale; continue; }
        r -= CHn;
        bks[r] = bk[r]*inv_scale;
    }
}

// ---------------- causal conv as 5 shifted K=64 GEMMs (MFMA) ------------------------
__global__ __launch_bounds__(256) void conv_kernel(
    const unsigned short* __restrict__ x_b,   // [B][T][64] bf16
    const unsigned short* __restrict__ w2,    // [KS][512][64] bf16 (pre-scaled)
    const float* __restrict__ bias,           // [512] pre-scaled, or nullptr
    unsigned short* __restrict__ outp)        // [B][H][T][64] bf16
{
    __shared__ __align__(16) unsigned short xs[68*64];
    const int t0 = blockIdx.x * 64;
    const int c0 = blockIdx.y * 64;
    const int b  = blockIdx.z;
    const int tid = threadIdx.x;

    // stage x[t0-4 .. t0+63][0..63] into LDS (swizzled), zeros for t<0
    for (int idx = tid; idx < 68*8; idx += 256) {
        int row = idx >> 3, g = idx & 7;
        int tg = t0 - 4 + row;
        bf16x8 v = {0,0,0,0,0,0,0,0};
        if (tg >= 0) v = *(const bf16x8*)&x_b[(b*Tn + tg)*Kn + g*8];
        *(bf16x8*)&xs[row*64 + ((g ^ (row & 7)) << 3)] = v;
    }
    __syncthreads();

    const int w = tid >> 6, l = tid & 63;
    const int lr = l & 15, lh = l >> 4;
    f32x4 acc[4] = {};
    #pragma unroll
    for (int j = 0; j < KSn; ++j) {
        #pragma unroll
        for (int kk = 0; kk < 2; ++kk) {
            int row = w*16 + lr + j;
            int g = (kk*4 + lh) ^ (row & 7);
            bf16x8 a = *(const bf16x8*)&xs[row*64 + g*8];
            #pragma unroll
            for (int n = 0; n < 4; ++n) {
                bf16x8 bf = *(const bf16x8*)&w2[(j*CHn + c0 + n*16 + lr)*Kn + kk*32 + lh*8];
                acc[n] = __builtin_amdgcn_mfma_f32_16x16x32_bf16(a, bf, acc[n], 0, 0, 0);
            }
        }
    }
    #pragma unroll
    for (int n = 0; n < 4; ++n) {
        int c = c0 + n*16 + lr;
        float bv = bias ? bias[c] : 0.0f;
        int h = c & 7, d = c >> 3;
        #pragma unroll
        for (int reg = 0; reg < 4; ++reg) {
            int t = t0 + w*16 + lh*4 + reg;
            outp[((b*Hn + h)*Tn + t)*Kn + d] = f2bf(acc[n][reg] + bv);
        }
    }
}

// ---------------- flash attention (causal), 64 Q-rows/block, 4 waves ----------------
__global__ __launch_bounds__(256) void attn_kernel(
    const unsigned short* __restrict__ q_s, const unsigned short* __restrict__ k_s,
    const unsigned short* __restrict__ v_s, unsigned short* __restrict__ attn)
{
    __shared__ __align__(16) unsigned short Vt[64*64];
    __shared__ __align__(16) unsigned short P[4*16*64];
    const int q0 = blockIdx.x * 64;
    const int bh = blockIdx.y;
    const unsigned short* qp = q_s + (size_t)bh*Tn*Kn;
    const unsigned short* kp = k_s + (size_t)bh*Tn*Kn;
    const unsigned short* vp = v_s + (size_t)bh*Tn*Kn;
    const int tid = threadIdx.x;
    const int w = tid >> 6, l = tid & 63;
    const int lr = l & 15, lh = l >> 4;

    // Q fragments, loop-invariant
    bf16x8 aq0 = *(const bf16x8*)&qp[(q0 + w*16 + lr)*Kn + 0  + lh*8];
    bf16x8 aq1 = *(const bf16x8*)&qp[(q0 + w*16 + lr)*Kn + 32 + lh*8];

    f32x4 acc_o[4] = {};
    float m_run[4] = {-1e30f, -1e30f, -1e30f, -1e30f};
    float l_run[4] = {0.f, 0.f, 0.f, 0.f};

    for (int s0 = 0; s0 <= q0; s0 += 64) {
        __syncthreads();  // protect Vt/P reuse from previous iteration
        // stage V tile transposed into LDS (swizzled)
        for (int idx = tid; idx < 64*8; idx += 256) {
            int keyl = idx >> 3, g = idx & 7;
            bf16x8 v = *(const bf16x8*)&vp[(s0 + keyl)*Kn + g*8];
            #pragma unroll
            for (int jj = 0; jj < 8; ++jj) {
                int d = g*8 + jj;
                Vt[(d*64 + keyl) ^ ((d & 7) << 3)] = (unsigned short)v[jj];
            }
        }
        // S = Q K^T (K fragments straight from global; [t][d] is the B^T pattern)
        f32x4 s_acc[4] = {};
        #pragma unroll
        for (int n = 0; n < 4; ++n) {
            bf16x8 b0 = *(const bf16x8*)&kp[(s0 + n*16 + lr)*Kn + 0  + lh*8];
            s_acc[n] = __builtin_amdgcn_mfma_f32_16x16x32_bf16(aq0, b0, s_acc[n], 0, 0, 0);
            bf16x8 b1 = *(const bf16x8*)&kp[(s0 + n*16 + lr)*Kn + 32 + lh*8];
            s_acc[n] = __builtin_amdgcn_mfma_f32_16x16x32_bf16(aq1, b1, s_acc[n], 0, 0, 0);
        }
        // causal mask on the diagonal tile
        if (s0 == q0) {
            #pragma unroll
            for (int n = 0; n < 4; ++n) {
                int s_g = s0 + n*16 + lr;
                #pragma unroll
                for (int reg = 0; reg < 4; ++reg) {
                    int q_g = q0 + w*16 + lh*4 + reg;
                    if (s_g > q_g) s_acc[n][reg] = -1e30f;
                }
            }
        }
        // online softmax (rows = (lh*4+reg), reduce across the 16 col-lanes)
        float pt[4][4];
        #pragma unroll
        for (int reg = 0; reg < 4; ++reg) {
            float m = fmaxf(fmaxf(s_acc[0][reg], s_acc[1][reg]),
                            fmaxf(s_acc[2][reg], s_acc[3][reg]));
            m = fmaxf(m, __shfl_xor(m, 1));
            m = fmaxf(m, __shfl_xor(m, 2));
            m = fmaxf(m, __shfl_xor(m, 4));
            m = fmaxf(m, __shfl_xor(m, 8));
            float m_new = fmaxf(m_run[reg], m);
            float alpha = __expf(m_run[reg] - m_new);
            m_run[reg] = m_new;
            float ssum = 0.f;
            #pragma unroll
            for (int n = 0; n < 4; ++n) {
                float p = __expf(s_acc[n][reg] - m_new);
                pt[n][reg] = p;
                ssum += p;
            }
            ssum += __shfl_xor(ssum, 1);
            ssum += __shfl_xor(ssum, 2);
            ssum += __shfl_xor(ssum, 4);
            ssum += __shfl_xor(ssum, 8);
            l_run[reg] = l_run[reg]*alpha + ssum;
            #pragma unroll
            for (int n = 0; n < 4; ++n) acc_o[n][reg] *= alpha;
        }
        // P -> LDS (swizzled) to re-shape C/D layout into A layout
        #pragma unroll
        for (int n = 0; n < 4; ++n) {
            #pragma unroll
            for (int reg = 0; reg < 4; ++reg) {
                int row = lh*4 + reg, col = n*16 + lr;
                P[w*1024 + ((row*64 + col) ^ ((row & 7) << 3))] = f2bf(pt[n][reg]);
            }
        }
        __syncthreads();  // Vt + P ready
        // O += P V
        #pragma unroll
        for (int kk = 0; kk < 2; ++kk) {
            int i0 = kk*32 + lh*8;
            bf16x8 ap = *(const bf16x8*)&P[w*1024 + lr*64 + (i0 ^ ((lr & 7) << 3))];
            #pragma unroll
            for (int n = 0; n < 4; ++n) {
                int d = n*16 + lr;
                bf16x8 bv = *(const bf16x8*)&Vt[d*64 + (i0 ^ ((d & 7) << 3))];
                acc_o[n] = __builtin_amdgcn_mfma_f32_16x16x32_bf16(ap, bv, acc_o[n], 0, 0, 0);
            }
        }
    }
    // epilogue: normalize + store [b][t][h*64+d] bf16
    const int b = bh >> 3, h = bh & 7;
    #pragma unroll
    for (int n = 0; n < 4; ++n) {
        #pragma unroll
        for (int reg = 0; reg < 4; ++reg) {
            int t = q0 + w*16 + lh*4 + reg;
            int d = n*16 + lr;
            attn[((size_t)(b*Tn + t))*CHn + h*Kn + d] = f2bf(acc_o[n][reg] / l_run[reg]);
        }
    }
}

// ---------------- output projection: [16384 x 512] @ [512 x 64] + bias --------------
__global__ __launch_bounds__(256) void proj_kernel(
    const unsigned short* __restrict__ attn, const unsigned short* __restrict__ wu_b,
    const float* __restrict__ bu, float* __restrict__ outp)
{
    const int r0 = blockIdx.x * 64;
    const int tid = threadIdx.x;
    const int w = tid >> 6, l = tid & 63;
    const int lr = l & 15, lh = l >> 4;
    f32x4 acc[4] = {};
    for (int kk = 0; kk < 16; ++kk) {
        bf16x8 a = *(const bf16x8*)&attn[(size_t)(r0 + w*16 + lr)*CHn + kk*32 + lh*8];
        #pragma unroll
        for (int n = 0; n < 4; ++n) {
            bf16x8 bf = *(const bf16x8*)&wu_b[(n*16 + lr)*CHn + kk*32 + lh*8];
            acc[n] = __builtin_amdgcn_mfma_f32_16x16x32_bf16(a, bf, acc[n], 0, 0, 0);
        }
    }
    #pragma unroll
    for (int n = 0; n < 4; ++n) {
        int ko = n*16 + lr;
        float bias = bu[ko];
        #pragma unroll
        for (int reg = 0; reg < 4; ++reg) {
            int row = r0 + w*16 + lh*4 + reg;
            outp[(size_t)row*Kn + ko] = acc[n][reg] + bias;
        }
    }
}

extern "C" void kernel_launch(void* const* d_in, const int* in_sizes, int n_in,
                              void* d_out, int out_size, void* d_ws, size_t ws_size,
                              hipStream_t stream)
{
    const float* x  = (const float*)d_in[0];
    const float* wq = (const float*)d_in[1];
    const float* bq = (const float*)d_in[2];
    const float* wk = (const float*)d_in[3];
    const float* bk = (const float*)d_in[4];
    const float* wv = (const float*)d_in[5];
    const float* wu = (const float*)d_in[6];
    const float* bu = (const float*)d_in[7];
    float* outp = (float*)d_out;

    char* ws = (char*)d_ws;
    size_t off = 0;
    auto alloc = [&](size_t bytes) {
        char* p = ws + off;
        off = (off + bytes + 255) & ~(size_t)255;
        return p;
    };
    unsigned short* x_b  = (unsigned short*)alloc((size_t)Bn*Tn*Kn*2);
    unsigned short* w2q  = (unsigned short*)alloc((size_t)KSn*CHn*Kn*2);
    unsigned short* w2k  = (unsigned short*)alloc((size_t)KSn*CHn*Kn*2);
    unsigned short* w2v  = (unsigned short*)alloc((size_t)KSn*CHn*Kn*2);
    unsigned short* wu_b = (unsigned short*)alloc((size_t)CHn*Kn*2);
    float*  bqs = (float*)alloc(CHn*4);
    float*  bks = (float*)alloc(CHn*4);
    unsigned short* q_s  = (unsigned short*)alloc((size_t)Bn*Hn*Tn*Kn*2);
    unsigned short* k_s  = (unsigned short*)alloc((size_t)Bn*Hn*Tn*Kn*2);
    unsigned short* v_s  = (unsigned short*)alloc((size_t)Bn*Hn*Tn*Kn*2);
    unsigned short* attn = (unsigned short*)alloc((size_t)Bn*Tn*CHn*2);

    prep_kernel<<<2048, 256, 0, stream>>>(x, wq, bq, wk, bk, wv, wu,
                                          x_b, w2q, w2k, w2v, wu_b, bqs, bks);
    dim3 cgrid(Tn/64, CHn/64, Bn);
    conv_kernel<<<cgrid, 256, 0, stream>>>(x_b, w2q, bqs, q_s);
    conv_kernel<<<cgrid, 256, 0, stream>>>(x_b, w2k, bks, k_s);
    conv_kernel<<<cgrid, 256, 0, stream>>>(x_b, w2v, nullptr, v_s);
    attn_kernel<<<dim3(Tn/64, Bn*Hn), 256, 0, stream>>>(q_s, k_s, v_s, attn);
    proj_kernel<<<(Bn*Tn)/64, 256, 0, stream>>>(attn, wu_b, bu, outp);
}

// Round 2
// 300.129 us; speedup vs baseline: 1.6227x; 1.6227x over previous
//
#include <hip/hip_runtime.h>
#include <hip/hip_bf16.h>

typedef __attribute__((ext_vector_type(8))) short bf16x8;
typedef __attribute__((ext_vector_type(4))) float f32x4;
typedef __attribute__((ext_vector_type(16))) float f32x16;
typedef __attribute__((ext_vector_type(4))) unsigned int u32x4;
typedef __attribute__((ext_vector_type(2))) unsigned int u32x2;

#define Bn 8
#define Tn 2048
#define Kn 64
#define Hn 8
#define KSn 5
#define CHn (Kn*Hn)  /* 512 */

__device__ __forceinline__ unsigned short f2bf(float f) {
    unsigned int x = __builtin_bit_cast(unsigned int, f);
    unsigned int r = (x + 0x7fffu + ((x >> 16) & 1u)) >> 16;
    return (unsigned short)r;
}

__device__ __forceinline__ unsigned int cvt_pk_bf16(float lo, float hi) {
    unsigned int r;
    asm("v_cvt_pk_bf16_f32 %0, %1, %2" : "=v"(r) : "v"(lo), "v"(hi));
    return r;
}

__device__ __forceinline__ u32x2 pl32swap(unsigned int x, unsigned int y, int hi) {
#if __has_builtin(__builtin_amdgcn_permlane32_swap)
    (void)hi;
    return __builtin_amdgcn_permlane32_swap(x, y, false, false);
#else
    unsigned int xs = (unsigned int)__shfl_xor((int)x, 32);
    unsigned int ys = (unsigned int)__shfl_xor((int)y, 32);
    u32x2 r;
    r[0] = hi ? xs : x;
    r[1] = hi ? y : ys;
    return r;
#endif
}

// ---------------- prep: dtype conversions + weight reformat + scale folding ---------
__global__ void prep_kernel(const float* __restrict__ x,
                            const float* __restrict__ wq, const float* __restrict__ bq,
                            const float* __restrict__ wk, const float* __restrict__ bk,
                            const float* __restrict__ wv,
                            const float* __restrict__ wu,
                            unsigned short* __restrict__ x_b,
                            unsigned short* __restrict__ w2q, unsigned short* __restrict__ w2k,
                            unsigned short* __restrict__ w2v,
                            unsigned short* __restrict__ wu_b,
                            float* __restrict__ bqs, float* __restrict__ bks)
{
    const float inv_scale = 0.35355339059327373f; // 64^-0.25
    const int N0 = Bn*Tn*Kn;          // 1048576
    const int N1 = KSn*CHn*Kn;        // 163840
    const int total = N0 + 3*N1 + CHn*Kn + 2*CHn;
    for (int i = blockIdx.x*blockDim.x + threadIdx.x; i < total; i += gridDim.x*blockDim.x) {
        if (i < N0) { x_b[i] = f2bf(x[i]); continue; }
        int r = i - N0;
        if (r < 3*N1) {
            int conv = r / N1; int rr = r - conv*N1;
            int j = rr / (CHn*Kn); int rc = rr - j*(CHn*Kn);
            int c = rc >> 6; int ic = rc & 63;
            const float* w = (conv==0) ? wq : ((conv==1) ? wk : wv);
            float s = (conv==2) ? 1.0f : inv_scale;
            unsigned short* dst = (conv==0) ? w2q : ((conv==1) ? w2k : w2v);
            dst[rr] = f2bf(w[(c*Kn + ic)*KSn + j] * s);
            continue;
        }
        r -= 3*N1;
        if (r < CHn*Kn) { wu_b[r] = f2bf(wu[r]); continue; }
        r -= CHn*Kn;
        if (r < CHn) { bqs[r] = bq[r]*inv_scale; continue; }
        r -= CHn;
        bks[r] = bk[r]*inv_scale;
    }
}

// ---------------- causal conv as 5 shifted K=64 GEMMs (MFMA) ------------------------
// mode 0: out[b][h][t][d]; mode 1: out[b][h][d][t] (transposed, for V)
__global__ __launch_bounds__(256) void conv_kernel(
    const unsigned short* __restrict__ x_b,   // [B][T][64] bf16
    const unsigned short* __restrict__ w2,    // [KS][512][64] bf16 (pre-scaled)
    const float* __restrict__ bias,           // [512] pre-scaled, or nullptr
    unsigned short* __restrict__ outp, int mode)
{
    __shared__ __align__(16) unsigned short xs[68*64];
    const int t0 = blockIdx.x * 64;
    const int c0 = blockIdx.y * 64;
    const int b  = blockIdx.z;
    const int tid = threadIdx.x;

    for (int idx = tid; idx < 68*8; idx += 256) {
        int row = idx >> 3, g = idx & 7;
        int tg = t0 - 4 + row;
        bf16x8 v = {0,0,0,0,0,0,0,0};
        if (tg >= 0) v = *(const bf16x8*)&x_b[(b*Tn + tg)*Kn + g*8];
        *(bf16x8*)&xs[row*64 + ((g ^ (row & 7)) << 3)] = v;
    }
    __syncthreads();

    const int w = tid >> 6, l = tid & 63;
    const int lr = l & 15, lh = l >> 4;
    f32x4 acc[4] = {};
    #pragma unroll
    for (int j = 0; j < KSn; ++j) {
        #pragma unroll
        for (int kk = 0; kk < 2; ++kk) {
            int row = w*16 + lr + j;
            int g = (kk*4 + lh) ^ (row & 7);
            bf16x8 a = *(const bf16x8*)&xs[row*64 + g*8];
            #pragma unroll
            for (int n = 0; n < 4; ++n) {
                bf16x8 bf = *(const bf16x8*)&w2[(j*CHn + c0 + n*16 + lr)*Kn + kk*32 + lh*8];
                acc[n] = __builtin_amdgcn_mfma_f32_16x16x32_bf16(a, bf, acc[n], 0, 0, 0);
            }
        }
    }
    #pragma unroll
    for (int n = 0; n < 4; ++n) {
        int c = c0 + n*16 + lr;
        float bv = bias ? bias[c] : 0.0f;
        int h = c & 7, d = c >> 3;
        #pragma unroll
        for (int reg = 0; reg < 4; ++reg) {
            int t = t0 + w*16 + lh*4 + reg;
            unsigned short val = f2bf(acc[n][reg] + bv);
            if (mode == 0) outp[((b*Hn + h)*Tn + t)*Kn + d] = val;
            else           outp[((b*Hn + h)*Kn + d)*Tn + t] = val;
        }
    }
}

// ---------------- flash attention v2: 32x32 swapped-QK, in-register softmax ---------
template<int NA, bool MASKED>
__device__ __forceinline__ void attn_tile(
    const unsigned short* __restrict__ kp, const unsigned short* __restrict__ vp,
    const bf16x8* qf, int s0, int qg, int lq, int hi,
    f32x16* o, float& m_run, float& l_run)
{
    // S' = K * Q^T : C[s][q], col=q=lane&31, row=s=(reg&3)+8*(reg>>2)+4*hi (+32*a)
    f32x16 s[NA];
    #pragma unroll
    for (int a = 0; a < NA; ++a) {
        s[a] = (f32x16)(0.0f);
        #pragma unroll
        for (int m = 0; m < 4; ++m) {
            bf16x8 ka = *(const bf16x8*)&kp[(s0 + a*32 + lq)*Kn + m*16 + hi*8];
            s[a] = __builtin_amdgcn_mfma_f32_32x32x16_bf16(ka, qf[m], s[a], 0, 0, 0);
        }
    }
    if (MASKED) {
        #pragma unroll
        for (int a = 0; a < NA; ++a)
            #pragma unroll
            for (int r = 0; r < 16; ++r) {
                int sg = s0 + a*32 + (r & 3) + 8*(r >> 2) + 4*hi;
                if (sg > qg) s[a][r] = -1e30f;
            }
    }
    // online softmax: one q per lane; halves merged via shfl_xor(32)
    float mt = -1e30f;
    #pragma unroll
    for (int a = 0; a < NA; ++a)
        #pragma unroll
        for (int r = 0; r < 16; ++r) mt = fmaxf(mt, s[a][r]);
    mt = fmaxf(mt, __shfl_xor(mt, 32));
    float mn = fmaxf(m_run, mt);
    float alpha = __expf(m_run - mn);
    m_run = mn;
    float sum = 0.f;
    #pragma unroll
    for (int a = 0; a < NA; ++a)
        #pragma unroll
        for (int r = 0; r < 16; ++r) {
            float p = __expf(s[a][r] - mn);
            s[a][r] = p;
            sum += p;
        }
    sum += __shfl_xor(sum, 32);
    l_run = l_run * alpha + sum;
    #pragma unroll
    for (int dn = 0; dn < 2; ++dn)
        #pragma unroll
        for (int r = 0; r < 16; ++r) o[dn][r] *= alpha;
    // repack P' (C/D layout) -> B-fragments, fully in-register
    unsigned int W[NA][8];
    #pragma unroll
    for (int a = 0; a < NA; ++a)
        #pragma unroll
        for (int rp = 0; rp < 8; ++rp)
            W[a][rp] = cvt_pk_bf16(s[a][2*rp], s[a][2*rp + 1]);
    u32x4 bw[2*NA];
    #pragma unroll
    for (int m = 0; m < 2*NA; ++m) {
        int a = m >> 1;
        #pragma unroll
        for (int jp = 0; jp < 2; ++jp) {
            u32x2 sw = pl32swap(W[a][jp + 4*(m & 1)], W[a][jp + 4*(m & 1) + 2], hi);
            bw[m][jp]     = sw[0];
            bw[m][jp + 2] = sw[1];
        }
    }
    // O^T += V^T * P' : A = Vt rows d (contiguous global), B = P' cols q
    #pragma unroll
    for (int dn = 0; dn < 2; ++dn)
        #pragma unroll
        for (int m = 0; m < 2*NA; ++m) {
            bf16x8 va = *(const bf16x8*)&vp[(dn*32 + lq)*Tn + s0 + m*16 + hi*8];
            o[dn] = __builtin_amdgcn_mfma_f32_32x32x16_bf16(
                va, __builtin_bit_cast(bf16x8, bw[m]), o[dn], 0, 0, 0);
        }
}

__global__ __launch_bounds__(256) void attn_kernel(
    const unsigned short* __restrict__ q_s, const unsigned short* __restrict__ k_s,
    const unsigned short* __restrict__ v_t, unsigned short* __restrict__ attn2)
{
    __shared__ __align__(16) unsigned char lds_raw[4*4096];
    const int tid = threadIdx.x;
    const int wid = tid >> 6, l = tid & 63;
    const int lq = l & 31, hi = l >> 5;
    const int bx = blockIdx.x;
    // XCD-aware: blockIdx&7 selects XCD; 8 consecutive heads per XCD (K+V = 4MB = L2)
    const int bh = (bx & 7)*8 + ((bx >> 3) & 7);
    const int pair = ((bx >> 6) & 7)*4 + wid;
    const unsigned short* qp = q_s + (size_t)bh*Tn*Kn;
    const unsigned short* kp = k_s + (size_t)bh*Tn*Kn;
    const unsigned short* vp = v_t + (size_t)bh*Kn*Tn;
    unsigned short* op = attn2 + (size_t)bh*Tn*Kn;
    char* myLds = (char*)lds_raw + wid*4096;

    for (int side = 0; side < 2; ++side) {
        const int qw = side ? (Tn - 32 - pair*32) : pair*32;  // causal pairing: uniform work
        const int qg = qw + lq;
        bf16x8 qf[4];
        #pragma unroll
        for (int m = 0; m < 4; ++m)
            qf[m] = *(const bf16x8*)&qp[(qw + lq)*Kn + m*16 + hi*8];
        f32x16 o[2];
        o[0] = (f32x16)(0.0f); o[1] = (f32x16)(0.0f);
        float m_run = -1e30f, l_run = 0.f;
        const int f64 = qw >> 6;
        for (int t = 0; t < f64; ++t)
            attn_tile<2, false>(kp, vp, qf, t*64, qg, lq, hi, o, m_run, l_run);
        if (qw & 32)
            attn_tile<1, false>(kp, vp, qf, f64*64, qg, lq, hi, o, m_run, l_run);
        attn_tile<1, true>(kp, vp, qf, qw, qg, lq, hi, o, m_run, l_run);
        // epilogue: normalize, transpose via per-wave LDS, coalesced b128 stores
        float inv_l = 1.0f / l_run;
        #pragma unroll
        for (int dn = 0; dn < 2; ++dn)
            #pragma unroll
            for (int e = 0; e < 16; e += 2) {
                int d0 = dn*32 + (e & 3) + 8*(e >> 2) + 4*hi;
                unsigned int wv = cvt_pk_bf16(o[dn][e]*inv_l, o[dn][e+1]*inv_l);
                *(unsigned int*)(myLds + ((lq*128 + d0*2) ^ ((lq & 7) << 4))) = wv;
            }
        // wave-internal LDS dependency; compiler inserts lgkmcnt waits
        int q2 = l >> 1, hf = l & 1;
        #pragma unroll
        for (int o4 = 0; o4 < 4; ++o4) {
            u32x4 vr = *(u32x4*)(myLds + ((q2*128 + hf*64 + o4*16) ^ ((q2 & 7) << 4)));
            *(u32x4*)&op[(qw + q2)*Kn + hf*32 + o4*8] = vr;
        }
    }
}

// ---------------- output projection: [16384 x 512] @ [512 x 64] + bias --------------
__global__ __launch_bounds__(256) void proj_kernel(
    const unsigned short* __restrict__ attn, const unsigned short* __restrict__ wu_b,
    const float* __restrict__ bu, float* __restrict__ outp)
{
    const int r0 = blockIdx.x * 64;
    const int tid = threadIdx.x;
    const int w = tid >> 6, l = tid & 63;
    const int lr = l & 15, lh = l >> 4;
    f32x4 acc[4] = {};
    const int r = r0 + w*16 + lr;
    const int bb = r >> 11, tt = r & 2047;
    for (int kk = 0; kk < 16; ++kk) {
        int ch = kk*32 + lh*8;
        int hh = ch >> 6, dd = ch & 63;
        bf16x8 a = *(const bf16x8*)&attn[(size_t)((bb*Hn + hh)*Tn + tt)*Kn + dd];
        #pragma unroll
        for (int n = 0; n < 4; ++n) {
            bf16x8 bf = *(const bf16x8*)&wu_b[(n*16 + lr)*CHn + kk*32 + lh*8];
            acc[n] = __builtin_amdgcn_mfma_f32_16x16x32_bf16(a, bf, acc[n], 0, 0, 0);
        }
    }
    #pragma unroll
    for (int n = 0; n < 4; ++n) {
        int ko = n*16 + lr;
        float bias = bu[ko];
        #pragma unroll
        for (int reg = 0; reg < 4; ++reg) {
            int row = r0 + w*16 + lh*4 + reg;
            outp[(size_t)row*Kn + ko] = acc[n][reg] + bias;
        }
    }
}

extern "C" void kernel_launch(void* const* d_in, const int* in_sizes, int n_in,
                              void* d_out, int out_size, void* d_ws, size_t ws_size,
                              hipStream_t stream)
{
    const float* x  = (const float*)d_in[0];
    const float* wq = (const float*)d_in[1];
    const float* bq = (const float*)d_in[2];
    const float* wk = (const float*)d_in[3];
    const float* bk = (const float*)d_in[4];
    const float* wv = (const float*)d_in[5];
    const float* wu = (const float*)d_in[6];
    const float* bu = (const float*)d_in[7];
    float* outp = (float*)d_out;

    char* ws = (char*)d_ws;
    size_t off = 0;
    auto alloc = [&](size_t bytes) {
        char* p = ws + off;
        off = (off + bytes + 255) & ~(size_t)255;
        return p;
    };
    unsigned short* x_b  = (unsigned short*)alloc((size_t)Bn*Tn*Kn*2);
    unsigned short* w2q  = (unsigned short*)alloc((size_t)KSn*CHn*Kn*2);
    unsigned short* w2k  = (unsigned short*)alloc((size_t)KSn*CHn*Kn*2);
    unsigned short* w2v  = (unsigned short*)alloc((size_t)KSn*CHn*Kn*2);
    unsigned short* wu_b = (unsigned short*)alloc((size_t)CHn*Kn*2);
    float*  bqs = (float*)alloc(CHn*4);
    float*  bks = (float*)alloc(CHn*4);
    unsigned short* q_s  = (unsigned short*)alloc((size_t)Bn*Hn*Tn*Kn*2);
    unsigned short* k_s  = (unsigned short*)alloc((size_t)Bn*Hn*Tn*Kn*2);
    unsigned short* v_t  = (unsigned short*)alloc((size_t)Bn*Hn*Tn*Kn*2);
    unsigned short* attn = (unsigned short*)alloc((size_t)Bn*Tn*CHn*2);

    prep_kernel<<<2048, 256, 0, stream>>>(x, wq, bq, wk, bk, wv, wu,
                                          x_b, w2q, w2k, w2v, wu_b, bqs, bks);
    dim3 cgrid(Tn/64, CHn/64, Bn);
    conv_kernel<<<cgrid, 256, 0, stream>>>(x_b, w2q, bqs, q_s, 0);
    conv_kernel<<<cgrid, 256, 0, stream>>>(x_b, w2k, bks, k_s, 0);
    conv_kernel<<<cgrid, 256, 0, stream>>>(x_b, w2v, nullptr, v_t, 1);
    attn_kernel<<<512, 256, 0, stream>>>(q_s, k_s, v_t, attn);
    proj_kernel<<<(Bn*Tn)/64, 256, 0, stream>>>(attn, wu_b, bu, outp);
}

// Round 3
// 284.826 us; speedup vs baseline: 1.7098x; 1.0537x over previous
//
#include <hip/hip_runtime.h>
#include <hip/hip_bf16.h>

typedef __attribute__((ext_vector_type(8))) short bf16x8;
typedef __attribute__((ext_vector_type(4))) float f32x4;
typedef __attribute__((ext_vector_type(16))) float f32x16;
typedef __attribute__((ext_vector_type(4))) unsigned int u32x4;
typedef __attribute__((ext_vector_type(2))) unsigned int u32x2;

#define Bn 8
#define Tn 2048
#define Kn 64
#define Hn 8
#define KSn 5
#define CHn 512

__device__ __forceinline__ unsigned short f2bf(float f) {
    unsigned int x = __builtin_bit_cast(unsigned int, f);
    unsigned int r = (x + 0x7fffu + ((x >> 16) & 1u)) >> 16;
    return (unsigned short)r;
}

__device__ __forceinline__ unsigned int cvt_pk_bf16(float lo, float hi) {
    unsigned int r;
    asm("v_cvt_pk_bf16_f32 %0, %1, %2" : "=v"(r) : "v"(lo), "v"(hi));
    return r;
}

__device__ __forceinline__ float fast_exp2(float x) {
#if __has_builtin(__builtin_amdgcn_exp2f)
    return __builtin_amdgcn_exp2f(x);
#else
    return exp2f(x);
#endif
}

__device__ __forceinline__ u32x2 pl32swap(unsigned int x, unsigned int y, int hi) {
#if __has_builtin(__builtin_amdgcn_permlane32_swap)
    (void)hi;
    return __builtin_amdgcn_permlane32_swap(x, y, false, false);
#else
    unsigned int xs = (unsigned int)__shfl_xor((int)x, 32);
    unsigned int ys = (unsigned int)__shfl_xor((int)y, 32);
    u32x2 r;
    r[0] = hi ? xs : x;
    r[1] = hi ? y : ys;
    return r;
#endif
}

// ---------------- prep: conversions + weight reformat + scale/log2e folding --------
__global__ void prep_kernel(const float* __restrict__ x,
                            const float* __restrict__ wq, const float* __restrict__ bq,
                            const float* __restrict__ wk, const float* __restrict__ bk,
                            const float* __restrict__ wv,
                            const float* __restrict__ wu,
                            unsigned short* __restrict__ x_b,
                            unsigned short* __restrict__ w2q, unsigned short* __restrict__ w2k,
                            unsigned short* __restrict__ w2v,
                            unsigned short* __restrict__ wu_b,
                            float* __restrict__ bqs, float* __restrict__ bks)
{
    // 64^-0.25 * sqrt(log2(e)): scores come out pre-multiplied by log2(e)
    const float inv_scale = 0.424660900144f;
    const int N0 = Bn*Tn*Kn;
    const int N1 = KSn*CHn*Kn;
    const int total = N0 + 3*N1 + CHn*Kn + 2*CHn;
    for (int i = blockIdx.x*blockDim.x + threadIdx.x; i < total; i += gridDim.x*blockDim.x) {
        if (i < N0) { x_b[i] = f2bf(x[i]); continue; }
        int r = i - N0;
        if (r < 3*N1) {
            int conv = r / N1; int rr = r - conv*N1;
            int j = rr / (CHn*Kn); int rc = rr - j*(CHn*Kn);
            int c = rc >> 6; int ic = rc & 63;
            const float* w = (conv==0) ? wq : ((conv==1) ? wk : wv);
            float s = (conv==2) ? 1.0f : inv_scale;
            unsigned short* dst = (conv==0) ? w2q : ((conv==1) ? w2k : w2v);
            dst[rr] = f2bf(w[(c*Kn + ic)*KSn + j] * s);
            continue;
        }
        r -= 3*N1;
        if (r < CHn*Kn) { wu_b[r] = f2bf(wu[r]); continue; }
        r -= CHn*Kn;
        if (r < CHn) { bqs[r] = bq[r]*inv_scale; continue; }
        r -= CHn;
        bks[r] = bk[r]*inv_scale;
    }
}

// ---------------- fused q/k/v causal conv (one x staging, 120 MFMA, LDS epilogue) ---
__global__ __launch_bounds__(256) void conv_fused(
    const unsigned short* __restrict__ x_b,
    const unsigned short* __restrict__ w2q,
    const unsigned short* __restrict__ w2k,
    const unsigned short* __restrict__ w2v,
    const float* __restrict__ bqs, const float* __restrict__ bks,
    unsigned short* __restrict__ q_s, unsigned short* __restrict__ k_s,
    unsigned short* __restrict__ v_t)
{
    __shared__ __align__(16) unsigned short xs[68*64];
    __shared__ __align__(16) unsigned short ts[64*64];
    const int t0 = blockIdx.x * 64;
    const int c0 = blockIdx.y * 64;
    const int b  = blockIdx.z;
    const int tid = threadIdx.x;

    for (int idx = tid; idx < 68*8; idx += 256) {
        int row = idx >> 3, g = idx & 7;
        int tg = t0 - 4 + row;
        bf16x8 v = {0,0,0,0,0,0,0,0};
        if (tg >= 0) v = *(const bf16x8*)&x_b[(b*Tn + tg)*Kn + g*8];
        *(bf16x8*)&xs[row*64 + ((g ^ (row & 7)) << 3)] = v;
    }
    __syncthreads();

    const int w = tid >> 6, l = tid & 63;
    const int lr = l & 15, lh = l >> 4;
    f32x4 aq[4] = {}, ak[4] = {}, av[4] = {};
    #pragma unroll
    for (int j = 0; j < KSn; ++j) {
        #pragma unroll
        for (int kk = 0; kk < 2; ++kk) {
            int row = w*16 + lr + j;
            int g = (kk*4 + lh) ^ (row & 7);
            bf16x8 a = *(const bf16x8*)&xs[row*64 + g*8];
            #pragma unroll
            for (int n = 0; n < 4; ++n) {
                int wi = (j*CHn + c0 + n*16 + lr)*Kn + kk*32 + lh*8;
                bf16x8 b0 = *(const bf16x8*)&w2q[wi];
                aq[n] = __builtin_amdgcn_mfma_f32_16x16x32_bf16(a, b0, aq[n], 0, 0, 0);
                bf16x8 b1 = *(const bf16x8*)&w2k[wi];
                ak[n] = __builtin_amdgcn_mfma_f32_16x16x32_bf16(a, b1, ak[n], 0, 0, 0);
                bf16x8 b2 = *(const bf16x8*)&w2v[wi];
                av[n] = __builtin_amdgcn_mfma_f32_16x16x32_bf16(a, b2, av[n], 0, 0, 0);
            }
        }
    }

    auto epi = [&](const f32x4* acc, const float* bias, unsigned short* out, int vmode) {
        #pragma unroll
        for (int n = 0; n < 4; ++n) {
            int cl = n*16 + lr;
            float bv = bias ? bias[c0 + cl] : 0.0f;
            #pragma unroll
            for (int reg = 0; reg < 4; ++reg) {
                int tl = w*16 + lh*4 + reg;
                ts[(tl*64 + cl) ^ ((tl & 7) << 3)] = f2bf(acc[n][reg] + bv);
            }
        }
        __syncthreads();
        if (!vmode) {
            // out[b][h][t][d]: per (h, t) pack 8 contiguous d -> one 16B store
            #pragma unroll
            for (int it = 0; it < 2; ++it) {
                int idx = tid + it*256;
                int tl = idx >> 3, hl = idx & 7;
                unsigned short tmp[8];
                #pragma unroll
                for (int dl = 0; dl < 8; ++dl)
                    tmp[dl] = ts[(tl*64 + hl + 8*dl) ^ ((tl & 7) << 3)];
                size_t el = ((size_t)(b*Hn + hl)*Tn + t0 + tl)*Kn + (c0 >> 3);
                *(u32x4*)&out[el] = *(u32x4*)tmp;
            }
        } else {
            // out[b][h][d][t]: per channel pack 8 contiguous t -> one 16B store
            #pragma unroll
            for (int it = 0; it < 2; ++it) {
                int idx = tid + it*256;
                int tc = idx >> 6, cl = idx & 63;
                int hl = cl & 7, dl = cl >> 3;
                unsigned short tmp[8];
                #pragma unroll
                for (int i = 0; i < 8; ++i)
                    tmp[i] = ts[((tc*8 + i)*64 + cl) ^ (((tc*8 + i) & 7) << 3)];
                size_t el = ((size_t)(b*Hn + hl)*Kn + (c0 >> 3) + dl)*Tn + t0 + tc*8;
                *(u32x4*)&out[el] = *(u32x4*)tmp;
            }
        }
        __syncthreads();
    };
    epi(aq, bqs, q_s, 0);
    epi(ak, bks, k_s, 0);
    epi(av, nullptr, v_t, 1);
}

// ---------------- flash attention: 32x32 swapped-QK, exp2 + defer-max ---------------
template<int NA, bool MASKED>
__device__ __forceinline__ void attn_tile(
    const unsigned short* __restrict__ kp, const unsigned short* __restrict__ vp,
    const bf16x8* qf, int s0, int qg, int lq, int hi,
    f32x16* o, float& m_run, float& l_run)
{
    f32x16 s[NA];
    #pragma unroll
    for (int a = 0; a < NA; ++a) {
        s[a] = (f32x16)(0.0f);
        #pragma unroll
        for (int m = 0; m < 4; ++m) {
            bf16x8 ka = *(const bf16x8*)&kp[(s0 + a*32 + lq)*Kn + m*16 + hi*8];
            s[a] = __builtin_amdgcn_mfma_f32_32x32x16_bf16(ka, qf[m], s[a], 0, 0, 0);
        }
    }
    if (MASKED) {
        #pragma unroll
        for (int a = 0; a < NA; ++a)
            #pragma unroll
            for (int r = 0; r < 16; ++r) {
                int sg = s0 + a*32 + (r & 3) + 8*(r >> 2) + 4*hi;
                if (sg > qg) s[a][r] = -1e30f;
            }
    }
    // tree max (short dependency chains)
    float pm[4] = {-1e30f, -1e30f, -1e30f, -1e30f};
    #pragma unroll
    for (int a = 0; a < NA; ++a)
        #pragma unroll
        for (int r = 0; r < 16; ++r) pm[r & 3] = fmaxf(pm[r & 3], s[a][r]);
    float mt = fmaxf(fmaxf(pm[0], pm[1]), fmaxf(pm[2], pm[3]));
    mt = fmaxf(mt, __shfl_xor(mt, 32));
    // defer-max: only rescale when max grew by >8 (log2 domain; P bounded by 256)
    if (!__all(mt <= m_run + 8.0f)) {
        float mn = fmaxf(m_run, mt);
        float alpha = fast_exp2(m_run - mn);
        m_run = mn;
        l_run *= alpha;
        #pragma unroll
        for (int dn = 0; dn < 2; ++dn)
            #pragma unroll
            for (int r = 0; r < 16; ++r) o[dn][r] *= alpha;
    }
    // p = 2^(s - m), tree sum
    float ps[4] = {0.f, 0.f, 0.f, 0.f};
    #pragma unroll
    for (int a = 0; a < NA; ++a)
        #pragma unroll
        for (int r = 0; r < 16; ++r) {
            float p = fast_exp2(s[a][r] - m_run);
            s[a][r] = p;
            ps[r & 3] += p;
        }
    float sum = (ps[0] + ps[1]) + (ps[2] + ps[3]);
    sum += __shfl_xor(sum, 32);
    l_run += sum;
    // repack P' (C/D layout) -> B-fragments in-register
    unsigned int W[NA][8];
    #pragma unroll
    for (int a = 0; a < NA; ++a)
        #pragma unroll
        for (int rp = 0; rp < 8; ++rp)
            W[a][rp] = cvt_pk_bf16(s[a][2*rp], s[a][2*rp + 1]);
    u32x4 bw[2*NA];
    #pragma unroll
    for (int m = 0; m < 2*NA; ++m) {
        int a = m >> 1;
        #pragma unroll
        for (int jp = 0; jp < 2; ++jp) {
            u32x2 sw = pl32swap(W[a][jp + 4*(m & 1)], W[a][jp + 4*(m & 1) + 2], hi);
            bw[m][jp]     = sw[0];
            bw[m][jp + 2] = sw[1];
        }
    }
    // O^T += V^T * P'
    #pragma unroll
    for (int dn = 0; dn < 2; ++dn)
        #pragma unroll
        for (int m = 0; m < 2*NA; ++m) {
            bf16x8 va = *(const bf16x8*)&vp[(dn*32 + lq)*Tn + s0 + m*16 + hi*8];
            o[dn] = __builtin_amdgcn_mfma_f32_32x32x16_bf16(
                va, __builtin_bit_cast(bf16x8, bw[m]), o[dn], 0, 0, 0);
        }
}

__global__ __launch_bounds__(256) void attn_kernel(
    const unsigned short* __restrict__ q_s, const unsigned short* __restrict__ k_s,
    const unsigned short* __restrict__ v_t, unsigned short* __restrict__ attn2)
{
    __shared__ __align__(16) unsigned char lds_raw[4*4096];
    const int tid = threadIdx.x;
    const int wid = tid >> 6, l = tid & 63;
    const int lq = l & 31, hi = l >> 5;
    const int bx = blockIdx.x;                 // 1024 blocks
    const int bh = (bx & 7)*8 + ((bx >> 3) & 7); // 8 heads per XCD (K+V fits L2)
    const int j  = bx >> 6;                    // 0..15
    // per-block light+heavy chunk mix: {2j, 2j+1, 62-2j, 63-2j}
    const int chunk = (wid & 2) ? (62 - 2*j + (wid & 1)) : (2*j + (wid & 1));
    const int qw = chunk * 32;
    const unsigned short* qp = q_s + (size_t)bh*Tn*Kn;
    const unsigned short* kp = k_s + (size_t)bh*Tn*Kn;
    const unsigned short* vp = v_t + (size_t)bh*Kn*Tn;
    unsigned short* op = attn2 + (size_t)bh*Tn*Kn;
    char* myLds = (char*)lds_raw + wid*4096;

    const int qg = qw + lq;
    bf16x8 qf[4];
    #pragma unroll
    for (int m = 0; m < 4; ++m)
        qf[m] = *(const bf16x8*)&qp[(qw + lq)*Kn + m*16 + hi*8];
    f32x16 o[2];
    o[0] = (f32x16)(0.0f); o[1] = (f32x16)(0.0f);
    float m_run = -1e30f, l_run = 0.f;
    const int f64 = qw >> 6;
    for (int t = 0; t < f64; ++t)
        attn_tile<2, false>(kp, vp, qf, t*64, qg, lq, hi, o, m_run, l_run);
    if (qw & 32)
        attn_tile<1, false>(kp, vp, qf, f64*64, qg, lq, hi, o, m_run, l_run);
    attn_tile<1, true>(kp, vp, qf, qw, qg, lq, hi, o, m_run, l_run);
    // epilogue: normalize, per-wave LDS transpose, coalesced 16B stores
    float inv_l = 1.0f / l_run;
    #pragma unroll
    for (int dn = 0; dn < 2; ++dn)
        #pragma unroll
        for (int e = 0; e < 16; e += 2) {
            int d0 = dn*32 + (e & 3) + 8*(e >> 2) + 4*hi;
            unsigned int wv = cvt_pk_bf16(o[dn][e]*inv_l, o[dn][e+1]*inv_l);
            *(unsigned int*)(myLds + ((lq*128 + d0*2) ^ ((lq & 7) << 4))) = wv;
        }
    int q2 = l >> 1, hf = l & 1;
    #pragma unroll
    for (int o4 = 0; o4 < 4; ++o4) {
        u32x4 vr = *(u32x4*)(myLds + ((q2*128 + hf*64 + o4*16) ^ ((q2 & 7) << 4)));
        *(u32x4*)&op[(qw + q2)*Kn + hf*32 + o4*8] = vr;
    }
}

// ---------------- output projection: 16 rows/block, 4-way K-split + LDS reduce ------
__global__ __launch_bounds__(256) void proj_kernel(
    const unsigned short* __restrict__ attn, const unsigned short* __restrict__ wu_b,
    const float* __restrict__ bu, float* __restrict__ outp)
{
    __shared__ float red[4*16*66];
    const int r0 = blockIdx.x * 16;
    const int tid = threadIdx.x;
    const int w = tid >> 6, l = tid & 63;
    const int lr = l & 15, lh = l >> 4;
    f32x4 acc[4] = {};
    const int r = r0 + lr;
    const int bb = r >> 11, tt = r & 2047;
    #pragma unroll
    for (int ki = 0; ki < 4; ++ki) {
        int kk = w*4 + ki;
        int ch = kk*32 + lh*8;
        int hh = ch >> 6, dd = ch & 63;
        bf16x8 a = *(const bf16x8*)&attn[(size_t)((bb*Hn + hh)*Tn + tt)*Kn + dd];
        #pragma unroll
        for (int n = 0; n < 4; ++n) {
            bf16x8 bf = *(const bf16x8*)&wu_b[(n*16 + lr)*CHn + ch];
            acc[n] = __builtin_amdgcn_mfma_f32_16x16x32_bf16(a, bf, acc[n], 0, 0, 0);
        }
    }
    #pragma unroll
    for (int n = 0; n < 4; ++n)
        #pragma unroll
        for (int reg = 0; reg < 4; ++reg)
            red[w*1056 + (lh*4 + reg)*66 + n*16 + lr] = acc[n][reg];
    __syncthreads();
    #pragma unroll
    for (int it = 0; it < 4; ++it) {
        int idx = tid + it*256;
        int rl = idx >> 6, ko = idx & 63;
        float s = red[rl*66 + ko] + red[1056 + rl*66 + ko]
                + red[2112 + rl*66 + ko] + red[3168 + rl*66 + ko] + bu[ko];
        outp[(size_t)(r0 + rl)*Kn + ko] = s;
    }
}

extern "C" void kernel_launch(void* const* d_in, const int* in_sizes, int n_in,
                              void* d_out, int out_size, void* d_ws, size_t ws_size,
                              hipStream_t stream)
{
    const float* x  = (const float*)d_in[0];
    const float* wq = (const float*)d_in[1];
    const float* bq = (const float*)d_in[2];
    const float* wk = (const float*)d_in[3];
    const float* bk = (const float*)d_in[4];
    const float* wv = (const float*)d_in[5];
    const float* wu = (const float*)d_in[6];
    const float* bu = (const float*)d_in[7];
    float* outp = (float*)d_out;

    char* ws = (char*)d_ws;
    size_t off = 0;
    auto alloc = [&](size_t bytes) {
        char* p = ws + off;
        off = (off + bytes + 255) & ~(size_t)255;
        return p;
    };
    unsigned short* x_b  = (unsigned short*)alloc((size_t)Bn*Tn*Kn*2);
    unsigned short* w2q  = (unsigned short*)alloc((size_t)KSn*CHn*Kn*2);
    unsigned short* w2k  = (unsigned short*)alloc((size_t)KSn*CHn*Kn*2);
    unsigned short* w2v  = (unsigned short*)alloc((size_t)KSn*CHn*Kn*2);
    unsigned short* wu_b = (unsigned short*)alloc((size_t)CHn*Kn*2);
    float*  bqs = (float*)alloc(CHn*4);
    float*  bks = (float*)alloc(CHn*4);
    unsigned short* q_s  = (unsigned short*)alloc((size_t)Bn*Hn*Tn*Kn*2);
    unsigned short* k_s  = (unsigned short*)alloc((size_t)Bn*Hn*Tn*Kn*2);
    unsigned short* v_t  = (unsigned short*)alloc((size_t)Bn*Hn*Tn*Kn*2);
    unsigned short* attn = (unsigned short*)alloc((size_t)Bn*Tn*CHn*2);

    prep_kernel<<<2048, 256, 0, stream>>>(x, wq, bq, wk, bk, wv, wu,
                                          x_b, w2q, w2k, w2v, wu_b, bqs, bks);
    conv_fused<<<dim3(Tn/64, CHn/64, Bn), 256, 0, stream>>>(
        x_b, w2q, w2k, w2v, bqs, bks, q_s, k_s, v_t);
    attn_kernel<<<1024, 256, 0, stream>>>(q_s, k_s, v_t, attn);
    proj_kernel<<<(Bn*Tn)/16, 256, 0, stream>>>(attn, wu_b, bu, outp);
}

// Round 4
// 187.653 us; speedup vs baseline: 2.5952x; 1.5178x over previous
//
#include <hip/hip_runtime.h>
#include <hip/hip_bf16.h>

typedef __attribute__((ext_vector_type(8))) short bf16x8;
typedef __attribute__((ext_vector_type(4))) float f32x4;
typedef __attribute__((ext_vector_type(16))) float f32x16;
typedef __attribute__((ext_vector_type(4))) unsigned int u32x4;
typedef __attribute__((ext_vector_type(2))) unsigned int u32x2;

#define Bn 8
#define Tn 2048
#define Kn 64
#define Hn 8
#define KSn 5
#define CHn 512
#define TPADn 2052  /* 4 zero rows + 2048 */

__device__ __forceinline__ unsigned short f2bf(float f) {
    unsigned int x = __builtin_bit_cast(unsigned int, f);
    unsigned int r = (x + 0x7fffu + ((x >> 16) & 1u)) >> 16;
    return (unsigned short)r;
}

__device__ __forceinline__ unsigned int cvt_pk_bf16(float lo, float hi) {
    unsigned int r;
    asm("v_cvt_pk_bf16_f32 %0, %1, %2" : "=v"(r) : "v"(lo), "v"(hi));
    return r;
}

__device__ __forceinline__ float fast_exp2(float x) {
#if __has_builtin(__builtin_amdgcn_exp2f)
    return __builtin_amdgcn_exp2f(x);
#else
    return exp2f(x);
#endif
}

__device__ __forceinline__ u32x2 pl32swap(unsigned int x, unsigned int y, int hi) {
#if __has_builtin(__builtin_amdgcn_permlane32_swap)
    (void)hi;
    return __builtin_amdgcn_permlane32_swap(x, y, false, false);
#else
    unsigned int xs = (unsigned int)__shfl_xor((int)x, 32);
    unsigned int ys = (unsigned int)__shfl_xor((int)y, 32);
    u32x2 r;
    r[0] = hi ? xs : x;
    r[1] = hi ? y : ys;
    return r;
#endif
}

__device__ __forceinline__ void gload_lds16(const void* g, void* l) {
    __builtin_amdgcn_global_load_lds(
        (const __attribute__((address_space(1))) void*)g,
        (__attribute__((address_space(3))) void*)l, 16, 0, 0);
}

// ---------------- prep: conversions + padded x + weight reformat + scale folding ----
__global__ void prep_kernel(const float* __restrict__ x,
                            const float* __restrict__ wq, const float* __restrict__ bq,
                            const float* __restrict__ wk, const float* __restrict__ bk,
                            const float* __restrict__ wv,
                            const float* __restrict__ wu,
                            unsigned short* __restrict__ x_pad,
                            unsigned short* __restrict__ w2q, unsigned short* __restrict__ w2k,
                            unsigned short* __restrict__ w2v,
                            unsigned short* __restrict__ wu_b,
                            float* __restrict__ bqs, float* __restrict__ bks)
{
    // 64^-0.25 * sqrt(log2(e)): scores come out pre-multiplied by log2(e)
    const float inv_scale = 0.424660900144f;
    const int N0 = Bn*TPADn*Kn;       // 1050624
    const int N1 = KSn*CHn*Kn;        // 163840
    const int total = N0 + 3*N1 + CHn*Kn + 2*CHn;
    for (int i = blockIdx.x*blockDim.x + threadIdx.x; i < total; i += gridDim.x*blockDim.x) {
        if (i < N0) {
            int b = i / (TPADn*Kn);
            int rem = i - b*(TPADn*Kn);
            int p = rem >> 6, ic = rem & 63;
            x_pad[i] = (p < 4) ? (unsigned short)0
                               : f2bf(x[((size_t)b*Tn + (p - 4))*Kn + ic]);
            continue;
        }
        int r = i - N0;
        if (r < 3*N1) {
            int conv = r / N1; int rr = r - conv*N1;
            int j = rr / (CHn*Kn); int rc = rr - j*(CHn*Kn);
            int c = rc >> 6; int ic = rc & 63;
            const float* w = (conv==0) ? wq : ((conv==1) ? wk : wv);
            float s = (conv==2) ? 1.0f : inv_scale;
            unsigned short* dst = (conv==0) ? w2q : ((conv==1) ? w2k : w2v);
            dst[rr] = f2bf(w[(c*Kn + ic)*KSn + j] * s);
            continue;
        }
        r -= 3*N1;
        if (r < CHn*Kn) { wu_b[r] = f2bf(wu[r]); continue; }
        r -= CHn*Kn;
        if (r < CHn) { bqs[r] = bq[r]*inv_scale; continue; }
        r -= CHn;
        bks[r] = bk[r]*inv_scale;
    }
}

// ---------------- conv v4: register weights, LDS-staged x (dbuf), 8 t-tiles/block ---
__global__ __launch_bounds__(256) void conv_v4(
    const unsigned short* __restrict__ x_pad,
    const unsigned short* __restrict__ w2q, const unsigned short* __restrict__ w2k,
    const unsigned short* __restrict__ w2v,
    const float* __restrict__ bqs, const float* __restrict__ bks,
    unsigned short* __restrict__ q_s, unsigned short* __restrict__ k_s,
    unsigned short* __restrict__ v_t)
{
    __shared__ __align__(16) unsigned short xs[2][72*64];
    __shared__ __align__(16) unsigned short ts[64*64];
    const int tg = blockIdx.x;        // 0..3  (group of 8 t-tiles)
    const int c0 = blockIdx.y * 64;   // channel slice
    const int zz = blockIdx.z;        // conv*8 + b
    const int conv = zz >> 3, b = zz & 7;
    const unsigned short* w2 = (conv==0) ? w2q : ((conv==1) ? w2k : w2v);
    const float* bias = (conv==0) ? bqs : ((conv==1) ? bks : nullptr);
    unsigned short* outp = (conv==0) ? q_s : ((conv==1) ? k_s : v_t);
    const int tid = threadIdx.x;
    const int wid = tid >> 6, l = tid & 63;
    const int lr = l & 15, lh = l >> 4;
    const int wt = wid & 1, wc = wid >> 1;

    // loop-invariant weight fragments: [j][kk][n2] (wave quadrant = 32c)
    bf16x8 wf[5][2][2];
    #pragma unroll
    for (int j = 0; j < 5; ++j)
        #pragma unroll
        for (int kk = 0; kk < 2; ++kk)
            #pragma unroll
            for (int n2 = 0; n2 < 2; ++n2)
                wf[j][kk][n2] = *(const bf16x8*)
                    &w2[(j*CHn + c0 + wc*32 + n2*16 + lr)*Kn + kk*32 + lh*8];
    float bv0 = bias ? bias[c0 + wc*32 + lr]      : 0.0f;
    float bv1 = bias ? bias[c0 + wc*32 + 16 + lr] : 0.0f;

    // stage 72 rows (p0..p0+71) into xs[buf]; source pre-swizzled, LDS linear
    const int swz_row = l >> 3;                 // LDS row & 7 (i*8 ≡ 0 mod 8)
    const int src_inrow = ((l & 7) << 4) ^ (swz_row << 4);
    auto stage = [&](int buf, int p0) {
        const char* base = (const char*)(x_pad + (size_t)b*TPADn*Kn);
        for (int i = wid; i < 9; i += 4) {
            const char* src = base + (size_t)(p0 + i*8 + swz_row)*128 + src_inrow;
            gload_lds16(src, (char*)&xs[buf][0] + i*1024 + l*16);
        }
    };
    // NOTE: gload_lds dest is wave-uniform base; the +l*16 is folded by HW (lane*size).
    // We pass base+i*1024 only; keep the pointer uniform:
    // (implemented below without l*16)

    int buf = 0;
    {   // stage tile 0
        const char* base = (const char*)(x_pad + (size_t)b*TPADn*Kn);
        int p0 = tg*512;
        for (int i = wid; i < 9; i += 4) {
            const char* src = base + (size_t)(p0 + i*8 + swz_row)*128 + src_inrow;
            gload_lds16(src, (char*)&xs[0][0] + i*1024);
        }
    }
    __syncthreads();

    for (int tt = 0; tt < 8; ++tt) {
        const int t0 = (tg*8 + tt)*64;
        if (tt < 7) {
            const char* base = (const char*)(x_pad + (size_t)b*TPADn*Kn);
            int p0 = t0 + 64;
            for (int i = wid; i < 9; i += 4) {
                const char* src = base + (size_t)(p0 + i*8 + swz_row)*128 + src_inrow;
                gload_lds16(src, (char*)&xs[buf^1][0] + i*1024);
            }
        }
        // compute 64x64 tile; wave quadrant (wt,wc)
        const char* xb = (const char*)&xs[buf][0];
        f32x4 acc[2][2] = {};
        #pragma unroll
        for (int j = 0; j < 5; ++j)
            #pragma unroll
            for (int kk = 0; kk < 2; ++kk) {
                #pragma unroll
                for (int m = 0; m < 2; ++m) {
                    int row = wt*32 + m*16 + lr + j;
                    bf16x8 a = *(const bf16x8*)
                        (xb + row*128 + ((kk*64 + lh*16) ^ ((row & 7) << 4)));
                    acc[m][0] = __builtin_amdgcn_mfma_f32_16x16x32_bf16(a, wf[j][kk][0], acc[m][0], 0, 0, 0);
                    acc[m][1] = __builtin_amdgcn_mfma_f32_16x16x32_bf16(a, wf[j][kk][1], acc[m][1], 0, 0, 0);
                }
            }
        __syncthreads();   // prev readout done; also orders xs[buf^1] stage vs next use
        #pragma unroll
        for (int m = 0; m < 2; ++m)
            #pragma unroll
            for (int n2 = 0; n2 < 2; ++n2) {
                float bv = n2 ? bv1 : bv0;
                int cl = wc*32 + n2*16 + lr;
                #pragma unroll
                for (int reg = 0; reg < 4; ++reg) {
                    int tl = wt*32 + m*16 + lh*4 + reg;
                    ts[(tl*64 + cl) ^ ((tl & 7) << 3)] = f2bf(acc[m][n2][reg] + bv);
                }
            }
        __syncthreads();
        if (conv < 2) {
            // out[b][h][t][d]: per (t,h) pack 8 contiguous d -> one 16B store
            #pragma unroll
            for (int it = 0; it < 2; ++it) {
                int idx = tid + it*256;
                int tl = idx >> 3, hl = idx & 7;
                unsigned short tmp[8];
                #pragma unroll
                for (int dl = 0; dl < 8; ++dl)
                    tmp[dl] = ts[(tl*64 + hl + 8*dl) ^ ((tl & 7) << 3)];
                size_t el = ((size_t)(b*Hn + hl)*Tn + t0 + tl)*Kn + (c0 >> 3);
                *(u32x4*)&outp[el] = *(u32x4*)tmp;
            }
        } else {
            // out[b][h][d][t]: per channel pack 8 contiguous t -> one 16B store
            #pragma unroll
            for (int it = 0; it < 2; ++it) {
                int idx = tid + it*256;
                int tc = idx >> 6, cl2 = idx & 63;
                int hl = cl2 & 7, dl = cl2 >> 3;
                unsigned short tmp[8];
                #pragma unroll
                for (int i2 = 0; i2 < 8; ++i2)
                    tmp[i2] = ts[((tc*8 + i2)*64 + cl2) ^ (((tc*8 + i2) & 7) << 3)];
                size_t el = ((size_t)(b*Hn + hl)*Kn + (c0 >> 3) + dl)*Tn + t0 + tc*8;
                *(u32x4*)&outp[el] = *(u32x4*)tmp;
            }
        }
        buf ^= 1;
    }
}

// ---------------- flash attention v4: 32-row chunk/wave, NA=1 tiles, load overlap ---
__global__ __launch_bounds__(256) void attn_kernel(
    const unsigned short* __restrict__ q_s, const unsigned short* __restrict__ k_s,
    const unsigned short* __restrict__ v_t, unsigned short* __restrict__ attn2)
{
    __shared__ __align__(16) unsigned char lds_raw[4*4096];
    const int tid = threadIdx.x;
    const int wid = tid >> 6, l = tid & 63;
    const int lq = l & 31, hi = l >> 5;
    const int bx = blockIdx.x;                   // 1024 blocks
    const int bh = (bx & 7)*8 + ((bx >> 3) & 7); // 8 heads per XCD (K+V fits L2)
    const int chunk = (15 - (bx >> 6))*4 + wid;  // heavy chunks first in dispatch order
    const int qw = chunk * 32;
    const unsigned short* qp = q_s + (size_t)bh*Tn*Kn;
    const unsigned short* kp = k_s + (size_t)bh*Tn*Kn;
    const unsigned short* vp = v_t + (size_t)bh*Kn*Tn;
    unsigned short* op = attn2 + (size_t)bh*Tn*Kn;
    char* myLds = (char*)lds_raw + wid*4096;
    const int qg = qw + lq;

    bf16x8 qf[4], kf[4];
    #pragma unroll
    for (int m = 0; m < 4; ++m) {
        qf[m] = *(const bf16x8*)&qp[(qw + lq)*Kn + m*16 + hi*8];
        kf[m] = *(const bf16x8*)&kp[lq*Kn + m*16 + hi*8];
    }
    f32x16 o0 = (f32x16)(0.0f), o1 = (f32x16)(0.0f);
    float m_run = -1e30f, l_run = 0.f;

    for (int t = 0; t <= chunk; ++t) {
        const int s0 = t*32;
        // V for current tile: issue early (covered by QK + softmax)
        bf16x8 vf0[2], vf1[2];
        #pragma unroll
        for (int m = 0; m < 2; ++m) {
            vf0[m] = *(const bf16x8*)&vp[lq*Tn        + s0 + m*16 + hi*8];
            vf1[m] = *(const bf16x8*)&vp[(32 + lq)*Tn + s0 + m*16 + hi*8];
        }
        // QK^T (swapped): C[s][q], one q per lane
        f32x16 s = (f32x16)(0.0f);
        #pragma unroll
        for (int m = 0; m < 4; ++m)
            s = __builtin_amdgcn_mfma_f32_32x32x16_bf16(kf[m], qf[m], s, 0, 0, 0);
        // reload kf for next tile right after last use (covered by softmax+PV)
        if (t < chunk) {
            #pragma unroll
            for (int m = 0; m < 4; ++m)
                kf[m] = *(const bf16x8*)&kp[(s0 + 32 + lq)*Kn + m*16 + hi*8];
        }
        if (t == chunk) {
            #pragma unroll
            for (int r = 0; r < 16; ++r) {
                int sg = s0 + (r & 3) + 8*(r >> 2) + 4*hi;
                if (sg > qg) s[r] = -1e30f;
            }
        }
        // max: tree reduce 16 -> 1, then cross-half
        float a8[8];
        #pragma unroll
        for (int r = 0; r < 8; ++r) a8[r] = fmaxf(s[r], s[r + 8]);
        float a4_0 = fmaxf(a8[0], a8[4]), a4_1 = fmaxf(a8[1], a8[5]);
        float a4_2 = fmaxf(a8[2], a8[6]), a4_3 = fmaxf(a8[3], a8[7]);
        float mt = fmaxf(fmaxf(a4_0, a4_1), fmaxf(a4_2, a4_3));
        mt = fmaxf(mt, __shfl_xor(mt, 32));
        // defer-max (log2 domain, THR=8)
        if (!__all(mt <= m_run + 8.0f)) {
            float mn = fmaxf(m_run, mt);
            float alpha = fast_exp2(m_run - mn);
            m_run = mn;
            l_run *= alpha;
            #pragma unroll
            for (int r = 0; r < 16; ++r) { o0[r] *= alpha; o1[r] *= alpha; }
        }
        float ps[4] = {0.f, 0.f, 0.f, 0.f};
        #pragma unroll
        for (int r = 0; r < 16; ++r) {
            float p = fast_exp2(s[r] - m_run);
            s[r] = p;
            ps[r & 3] += p;
        }
        float sum = (ps[0] + ps[1]) + (ps[2] + ps[3]);
        sum += __shfl_xor(sum, 32);
        l_run += sum;
        // repack P' -> B fragments (in-register)
        unsigned int W[8];
        #pragma unroll
        for (int rp = 0; rp < 8; ++rp)
            W[rp] = cvt_pk_bf16(s[2*rp], s[2*rp + 1]);
        u32x4 bw[2];
        #pragma unroll
        for (int m = 0; m < 2; ++m)
            #pragma unroll
            for (int jp = 0; jp < 2; ++jp) {
                u32x2 sw = pl32swap(W[jp + 4*m], W[jp + 4*m + 2], hi);
                bw[m][jp]     = sw[0];
                bw[m][jp + 2] = sw[1];
            }
        // O^T += V^T * P'
        #pragma unroll
        for (int m = 0; m < 2; ++m) {
            o0 = __builtin_amdgcn_mfma_f32_32x32x16_bf16(vf0[m], __builtin_bit_cast(bf16x8, bw[m]), o0, 0, 0, 0);
            o1 = __builtin_amdgcn_mfma_f32_32x32x16_bf16(vf1[m], __builtin_bit_cast(bf16x8, bw[m]), o1, 0, 0, 0);
        }
    }
    // epilogue: normalize, per-wave LDS transpose, coalesced 16B stores
    float inv_l = 1.0f / l_run;
    #pragma unroll
    for (int e = 0; e < 16; e += 2) {
        int dd = (e & 3) + 8*(e >> 2) + 4*hi;
        unsigned int wv0 = cvt_pk_bf16(o0[e]*inv_l, o0[e+1]*inv_l);
        *(unsigned int*)(myLds + ((lq*128 + dd*2)      ^ ((lq & 7) << 4))) = wv0;
        unsigned int wv1 = cvt_pk_bf16(o1[e]*inv_l, o1[e+1]*inv_l);
        *(unsigned int*)(myLds + ((lq*128 + 64 + dd*2) ^ ((lq & 7) << 4))) = wv1;
    }
    int q2 = l >> 1, hf = l & 1;
    #pragma unroll
    for (int o4 = 0; o4 < 4; ++o4) {
        u32x4 vr = *(u32x4*)(myLds + ((q2*128 + hf*64 + o4*16) ^ ((q2 & 7) << 4)));
        *(u32x4*)&op[(qw + q2)*Kn + hf*32 + o4*8] = vr;
    }
}

// ---------------- output projection: 16 rows/block, 4-way K-split + LDS reduce ------
__global__ __launch_bounds__(256) void proj_kernel(
    const unsigned short* __restrict__ attn, const unsigned short* __restrict__ wu_b,
    const float* __restrict__ bu, float* __restrict__ outp)
{
    __shared__ float red[4*16*66];
    const int r0 = blockIdx.x * 16;
    const int tid = threadIdx.x;
    const int w = tid >> 6, l = tid & 63;
    const int lr = l & 15, lh = l >> 4;
    f32x4 acc[4] = {};
    const int r = r0 + lr;
    const int bb = r >> 11, tt = r & 2047;
    #pragma unroll
    for (int ki = 0; ki < 4; ++ki) {
        int kk = w*4 + ki;
        int ch = kk*32 + lh*8;
        int hh = ch >> 6, dd = ch & 63;
        bf16x8 a = *(const bf16x8*)&attn[(size_t)((bb*Hn + hh)*Tn + tt)*Kn + dd];
        #pragma unroll
        for (int n = 0; n < 4; ++n) {
            bf16x8 bf = *(const bf16x8*)&wu_b[(n*16 + lr)*CHn + ch];
            acc[n] = __builtin_amdgcn_mfma_f32_16x16x32_bf16(a, bf, acc[n], 0, 0, 0);
        }
    }
    #pragma unroll
    for (int n = 0; n < 4; ++n)
        #pragma unroll
        for (int reg = 0; reg < 4; ++reg)
            red[w*1056 + (lh*4 + reg)*66 + n*16 + lr] = acc[n][reg];
    __syncthreads();
    #pragma unroll
    for (int it = 0; it < 4; ++it) {
        int idx = tid + it*256;
        int rl = idx >> 6, ko = idx & 63;
        float s = red[rl*66 + ko] + red[1056 + rl*66 + ko]
                + red[2112 + rl*66 + ko] + red[3168 + rl*66 + ko] + bu[ko];
        outp[(size_t)(r0 + rl)*Kn + ko] = s;
    }
}

extern "C" void kernel_launch(void* const* d_in, const int* in_sizes, int n_in,
                              void* d_out, int out_size, void* d_ws, size_t ws_size,
                              hipStream_t stream)
{
    const float* x  = (const float*)d_in[0];
    const float* wq = (const float*)d_in[1];
    const float* bq = (const float*)d_in[2];
    const float* wk = (const float*)d_in[3];
    const float* bk = (const float*)d_in[4];
    const float* wv = (const float*)d_in[5];
    const float* wu = (const float*)d_in[6];
    const float* bu = (const float*)d_in[7];
    float* outp = (float*)d_out;

    char* ws = (char*)d_ws;
    size_t off = 0;
    auto alloc = [&](size_t bytes) {
        char* p = ws + off;
        off = (off + bytes + 255) & ~(size_t)255;
        return p;
    };
    unsigned short* x_pad = (unsigned short*)alloc((size_t)Bn*TPADn*Kn*2);
    unsigned short* w2q  = (unsigned short*)alloc((size_t)KSn*CHn*Kn*2);
    unsigned short* w2k  = (unsigned short*)alloc((size_t)KSn*CHn*Kn*2);
    unsigned short* w2v  = (unsigned short*)alloc((size_t)KSn*CHn*Kn*2);
    unsigned short* wu_b = (unsigned short*)alloc((size_t)CHn*Kn*2);
    float*  bqs = (float*)alloc(CHn*4);
    float*  bks = (float*)alloc(CHn*4);
    unsigned short* q_s  = (unsigned short*)alloc((size_t)Bn*Hn*Tn*Kn*2);
    unsigned short* k_s  = (unsigned short*)alloc((size_t)Bn*Hn*Tn*Kn*2);
    unsigned short* v_t  = (unsigned short*)alloc((size_t)Bn*Hn*Tn*Kn*2);
    unsigned short* attn = (unsigned short*)alloc((size_t)Bn*Tn*CHn*2);

    prep_kernel<<<2048, 256, 0, stream>>>(x, wq, bq, wk, bk, wv, wu,
                                          x_pad, w2q, w2k, w2v, wu_b, bqs, bks);
    conv_v4<<<dim3(4, 8, 24), 256, 0, stream>>>(
        x_pad, w2q, w2k, w2v, bqs, bks, q_s, k_s, v_t);
    attn_kernel<<<1024, 256, 0, stream>>>(q_s, k_s, v_t, attn);
    proj_kernel<<<(Bn*Tn)/16, 256, 0, stream>>>(attn, wu_b, bu, outp);
}

// Round 7
// 180.262 us; speedup vs baseline: 2.7016x; 1.0410x over previous
//
#include <hip/hip_runtime.h>
#include <hip/hip_bf16.h>

typedef __attribute__((ext_vector_type(8))) short bf16x8;
typedef __attribute__((ext_vector_type(4))) float f32x4;
typedef __attribute__((ext_vector_type(16))) float f32x16;
typedef __attribute__((ext_vector_type(4))) unsigned int u32x4;
typedef __attribute__((ext_vector_type(2))) unsigned int u32x2;

#define Bn 8
#define Tn 2048
#define Kn 64
#define Hn 8
#define KSn 5
#define CHn 512
#define TPADn 2052  /* 4 zero rows + 2048 */

__device__ __forceinline__ unsigned short f2bf(float f) {
    unsigned int x = __builtin_bit_cast(unsigned int, f);
    unsigned int r = (x + 0x7fffu + ((x >> 16) & 1u)) >> 16;
    return (unsigned short)r;
}

__device__ __forceinline__ unsigned int cvt_pk_bf16(float lo, float hi) {
    unsigned int r;
    asm("v_cvt_pk_bf16_f32 %0, %1, %2" : "=v"(r) : "v"(lo), "v"(hi));
    return r;
}

__device__ __forceinline__ float fast_exp2(float x) {
#if __has_builtin(__builtin_amdgcn_exp2f)
    return __builtin_amdgcn_exp2f(x);
#else
    return exp2f(x);
#endif
}

// cross-half (lane ^ 32) merges: validated shfl_xor path (rounds 1-4).
// permlane32_swap self-merge variants failed twice (r5: 0.131, r6: NaN) - do not use.
__device__ __forceinline__ float xhalf_max(float v) {
    return fmaxf(v, __shfl_xor(v, 32));
}
__device__ __forceinline__ float xhalf_add(float v) {
    return v + __shfl_xor(v, 32);
}

// distinct-operand two-register permute (validated in P-repack since round 1)
__device__ __forceinline__ u32x2 pl32swap(unsigned int x, unsigned int y) {
#if __has_builtin(__builtin_amdgcn_permlane32_swap)
    return __builtin_amdgcn_permlane32_swap(x, y, false, false);
#else
    unsigned int xs = (unsigned int)__shfl_xor((int)x, 32);
    unsigned int ys = (unsigned int)__shfl_xor((int)y, 32);
    int hi = (threadIdx.x & 63) >> 5;
    u32x2 r;
    r[0] = hi ? ys : x;   // {x.lo | y.lo}
    r[1] = hi ? y : xs;   // {x.hi | y.hi}
    return r;
#endif
}

__device__ __forceinline__ void gload_lds16(const void* g, void* l) {
    __builtin_amdgcn_global_load_lds(
        (const __attribute__((address_space(1))) void*)g,
        (__attribute__((address_space(3))) void*)l, 16, 0, 0);
}

// ---------------- prep: conversions + padded x + weight reformat + scale folding ----
__global__ void prep_kernel(const float* __restrict__ x,
                            const float* __restrict__ wq, const float* __restrict__ bq,
                            const float* __restrict__ wk, const float* __restrict__ bk,
                            const float* __restrict__ wv,
                            const float* __restrict__ wu,
                            unsigned short* __restrict__ x_pad,
                            unsigned short* __restrict__ w2q, unsigned short* __restrict__ w2k,
                            unsigned short* __restrict__ w2v,
                            unsigned short* __restrict__ wu_b,
                            float* __restrict__ bqs, float* __restrict__ bks)
{
    // 64^-0.25 * sqrt(log2(e)): scores come out pre-multiplied by log2(e)
    const float inv_scale = 0.424660900144f;
    const int N0 = Bn*TPADn*Kn;
    const int N1 = KSn*CHn*Kn;
    const int total = N0 + 3*N1 + CHn*Kn + 2*CHn;
    for (int i = blockIdx.x*blockDim.x + threadIdx.x; i < total; i += gridDim.x*blockDim.x) {
        if (i < N0) {
            int b = i / (TPADn*Kn);
            int rem = i - b*(TPADn*Kn);
            int p = rem >> 6, ic = rem & 63;
            x_pad[i] = (p < 4) ? (unsigned short)0
                               : f2bf(x[((size_t)b*Tn + (p - 4))*Kn + ic]);
            continue;
        }
        int r = i - N0;
        if (r < 3*N1) {
            int conv = r / N1; int rr = r - conv*N1;
            int j = rr / (CHn*Kn); int rc = rr - j*(CHn*Kn);
            int c = rc >> 6; int ic = rc & 63;
            const float* w = (conv==0) ? wq : ((conv==1) ? wk : wv);
            float s = (conv==2) ? 1.0f : inv_scale;
            unsigned short* dst = (conv==0) ? w2q : ((conv==1) ? w2k : w2v);
            dst[rr] = f2bf(w[(c*Kn + ic)*KSn + j] * s);
            continue;
        }
        r -= 3*N1;
        if (r < CHn*Kn) { wu_b[r] = f2bf(wu[r]); continue; }
        r -= CHn*Kn;
        if (r < CHn) { bqs[r] = bq[r]*inv_scale; continue; }
        r -= CHn;
        bks[r] = bk[r]*inv_scale;
    }
}

// ---------------- conv v4: register weights, LDS-staged x (dbuf), 8 t-tiles/block ---
__global__ __launch_bounds__(256) void conv_v4(
    const unsigned short* __restrict__ x_pad,
    const unsigned short* __restrict__ w2q, const unsigned short* __restrict__ w2k,
    const unsigned short* __restrict__ w2v,
    const float* __restrict__ bqs, const float* __restrict__ bks,
    unsigned short* __restrict__ q_s, unsigned short* __restrict__ k_s,
    unsigned short* __restrict__ v_t)
{
    __shared__ __align__(16) unsigned short xs[2][72*64];
    __shared__ __align__(16) unsigned short ts[64*64];
    const int tg = blockIdx.x;
    const int c0 = blockIdx.y * 64;
    const int zz = blockIdx.z;
    const int conv = zz >> 3, b = zz & 7;
    const unsigned short* w2 = (conv==0) ? w2q : ((conv==1) ? w2k : w2v);
    const float* bias = (conv==0) ? bqs : ((conv==1) ? bks : nullptr);
    unsigned short* outp = (conv==0) ? q_s : ((conv==1) ? k_s : v_t);
    const int tid = threadIdx.x;
    const int wid = tid >> 6, l = tid & 63;
    const int lr = l & 15, lh = l >> 4;
    const int wt = wid & 1, wc = wid >> 1;

    bf16x8 wf[5][2][2];
    #pragma unroll
    for (int j = 0; j < 5; ++j)
        #pragma unroll
        for (int kk = 0; kk < 2; ++kk)
            #pragma unroll
            for (int n2 = 0; n2 < 2; ++n2)
                wf[j][kk][n2] = *(const bf16x8*)
                    &w2[(j*CHn + c0 + wc*32 + n2*16 + lr)*Kn + kk*32 + lh*8];
    float bv0 = bias ? bias[c0 + wc*32 + lr]      : 0.0f;
    float bv1 = bias ? bias[c0 + wc*32 + 16 + lr] : 0.0f;

    const int swz_row = l >> 3;
    const int src_inrow = ((l & 7) << 4) ^ (swz_row << 4);

    int buf = 0;
    {
        const char* base = (const char*)(x_pad + (size_t)b*TPADn*Kn);
        int p0 = tg*512;
        for (int i = wid; i < 9; i += 4) {
            const char* src = base + (size_t)(p0 + i*8 + swz_row)*128 + src_inrow;
            gload_lds16(src, (char*)&xs[0][0] + i*1024);
        }
    }
    __syncthreads();

    for (int tt = 0; tt < 8; ++tt) {
        const int t0 = (tg*8 + tt)*64;
        if (tt < 7) {
            const char* base = (const char*)(x_pad + (size_t)b*TPADn*Kn);
            int p0 = t0 + 64;
            for (int i = wid; i < 9; i += 4) {
                const char* src = base + (size_t)(p0 + i*8 + swz_row)*128 + src_inrow;
                gload_lds16(src, (char*)&xs[buf^1][0] + i*1024);
            }
        }
        const char* xb = (const char*)&xs[buf][0];
        f32x4 acc[2][2] = {};
        #pragma unroll
        for (int j = 0; j < 5; ++j)
            #pragma unroll
            for (int kk = 0; kk < 2; ++kk) {
                #pragma unroll
                for (int m = 0; m < 2; ++m) {
                    int row = wt*32 + m*16 + lr + j;
                    bf16x8 a = *(const bf16x8*)
                        (xb + row*128 + ((kk*64 + lh*16) ^ ((row & 7) << 4)));
                    acc[m][0] = __builtin_amdgcn_mfma_f32_16x16x32_bf16(a, wf[j][kk][0], acc[m][0], 0, 0, 0);
                    acc[m][1] = __builtin_amdgcn_mfma_f32_16x16x32_bf16(a, wf[j][kk][1], acc[m][1], 0, 0, 0);
                }
            }
        __syncthreads();
        #pragma unroll
        for (int m = 0; m < 2; ++m)
            #pragma unroll
            for (int n2 = 0; n2 < 2; ++n2) {
                float bv = n2 ? bv1 : bv0;
                int cl = wc*32 + n2*16 + lr;
                #pragma unroll
                for (int reg = 0; reg < 4; ++reg) {
                    int tl = wt*32 + m*16 + lh*4 + reg;
                    ts[(tl*64 + cl) ^ ((tl & 7) << 3)] = f2bf(acc[m][n2][reg] + bv);
                }
            }
        __syncthreads();
        if (conv < 2) {
            #pragma unroll
            for (int it = 0; it < 2; ++it) {
                int idx = tid + it*256;
                int tl = idx >> 3, hl = idx & 7;
                unsigned short tmp[8];
                #pragma unroll
                for (int dl = 0; dl < 8; ++dl)
                    tmp[dl] = ts[(tl*64 + hl + 8*dl) ^ ((tl & 7) << 3)];
                size_t el = ((size_t)(b*Hn + hl)*Tn + t0 + tl)*Kn + (c0 >> 3);
                *(u32x4*)&outp[el] = *(u32x4*)tmp;
            }
        } else {
            #pragma unroll
            for (int it = 0; it < 2; ++it) {
                int idx = tid + it*256;
                int tc = idx >> 6, cl2 = idx & 63;
                int hl = cl2 & 7, dl = cl2 >> 3;
                unsigned short tmp[8];
                #pragma unroll
                for (int i2 = 0; i2 < 8; ++i2)
                    tmp[i2] = ts[((tc*8 + i2)*64 + cl2) ^ (((tc*8 + i2) & 7) << 3)];
                size_t el = ((size_t)(b*Hn + hl)*Kn + (c0 >> 3) + dl)*Tn + t0 + tc*8;
                *(u32x4*)&outp[el] = *(u32x4*)tmp;
            }
        }
        buf ^= 1;
    }
}

// ---------------- flash attention v5c: reg-dbuf K/V prefetch, shfl softmax ----------
__global__ __launch_bounds__(256, 3) void attn_kernel(
    const unsigned short* __restrict__ q_s, const unsigned short* __restrict__ k_s,
    const unsigned short* __restrict__ v_t, unsigned short* __restrict__ attn2)
{
    __shared__ __align__(16) unsigned char lds_raw[4*4096];
    const int tid = threadIdx.x;
    const int wid = tid >> 6, l = tid & 63;
    const int lq = l & 31, hi = l >> 5;
    const int bx = blockIdx.x;                   // 1024 blocks
    const int bh = (bx & 7)*8 + ((bx >> 3) & 7); // 8 heads per XCD (K+V fits L2)
    // balanced chunk-group permutation: {P[g],P[g+4],P[g+8],P[g+12]} sums to 30
    const int j = bx >> 6, gg = j >> 2, ii = j & 3;
    const int pg = (gg==0) ? 15-ii : (gg==1) ? ii : (gg==2) ? 8+ii : 7-ii;
    const int chunk = pg*4 + wid;
    const int qw = chunk * 32;
    const unsigned short* qp = q_s + (size_t)bh*Tn*Kn;
    const unsigned short* kp = k_s + (size_t)bh*Tn*Kn;
    const unsigned short* vp = v_t + (size_t)bh*Kn*Tn;
    unsigned short* op = attn2 + (size_t)bh*Tn*Kn;
    char* myLds = (char*)lds_raw + wid*4096;
    const int qg = qw + lq;

    bf16x8 qf[4];
    #pragma unroll
    for (int m = 0; m < 4; ++m)
        qf[m] = *(const bf16x8*)&qp[(qw + lq)*Kn + m*16 + hi*8];

    f32x16 o0 = (f32x16)(0.0f), o1 = (f32x16)(0.0f);
    float m_run = -1e30f, l_run = 0.f;

    // double-buffered K/V fragments (named, statically indexed)
    bf16x8 kbA[4], kbB[4], vbA[2][2], vbB[2][2];
    #pragma unroll
    for (int m = 0; m < 4; ++m)
        kbA[m] = *(const bf16x8*)&kp[lq*Kn + m*16 + hi*8];
    #pragma unroll
    for (int m = 0; m < 2; ++m) {
        vbA[0][m] = *(const bf16x8*)&vp[lq*Tn        + m*16 + hi*8];
        vbA[1][m] = *(const bf16x8*)&vp[(32 + lq)*Tn + m*16 + hi*8];
    }
    if (chunk >= 1) {
        #pragma unroll
        for (int m = 0; m < 4; ++m)
            kbB[m] = *(const bf16x8*)&kp[(32 + lq)*Kn + m*16 + hi*8];
        #pragma unroll
        for (int m = 0; m < 2; ++m) {
            vbB[0][m] = *(const bf16x8*)&vp[lq*Tn        + 32 + m*16 + hi*8];
            vbB[1][m] = *(const bf16x8*)&vp[(32 + lq)*Tn + 32 + m*16 + hi*8];
        }
    }

    auto tile = [&](int t, bf16x8 (&kb)[4], bf16x8 (&vb)[2][2]) {
        const int s0 = t*32;
        // QK^T (swapped): C[s][q], one q-column per lane
        f32x16 s = (f32x16)(0.0f);
        #pragma unroll
        for (int m = 0; m < 4; ++m)
            s = __builtin_amdgcn_mfma_f32_32x32x16_bf16(kb[m], qf[m], s, 0, 0, 0);
        // prefetch K(t+2) into the just-freed buffer (~1.5 tiles of cover)
        if (t + 2 <= chunk) {
            #pragma unroll
            for (int m = 0; m < 4; ++m)
                kb[m] = *(const bf16x8*)&kp[(s0 + 64 + lq)*Kn + m*16 + hi*8];
        }
        if (t == chunk) {
            #pragma unroll
            for (int r = 0; r < 16; ++r) {
                int sg = s0 + (r & 3) + 8*(r >> 2) + 4*hi;
                if (sg > qg) s[r] = -1e30f;
            }
        }
        // tree max + cross-half merge (validated shfl path)
        float a8[8];
        #pragma unroll
        for (int r = 0; r < 8; ++r) a8[r] = fmaxf(s[r], s[r + 8]);
        float a4_0 = fmaxf(a8[0], a8[4]), a4_1 = fmaxf(a8[1], a8[5]);
        float a4_2 = fmaxf(a8[2], a8[6]), a4_3 = fmaxf(a8[3], a8[7]);
        float mt = fmaxf(fmaxf(a4_0, a4_1), fmaxf(a4_2, a4_3));
        mt = xhalf_max(mt);
        // defer-max (log2 domain, THR=8)
        if (!__all(mt <= m_run + 8.0f)) {
            float mn = fmaxf(m_run, mt);
            float alpha = fast_exp2(m_run - mn);
            m_run = mn;
            l_run *= alpha;
            #pragma unroll
            for (int r = 0; r < 16; ++r) { o0[r] *= alpha; o1[r] *= alpha; }
        }
        float ps[4] = {0.f, 0.f, 0.f, 0.f};
        #pragma unroll
        for (int r = 0; r < 16; ++r) {
            float p = fast_exp2(s[r] - m_run);
            s[r] = p;
            ps[r & 3] += p;
        }
        float sum = (ps[0] + ps[1]) + (ps[2] + ps[3]);
        l_run += xhalf_add(sum);
        // repack P' -> B fragments (in-register; distinct-operand permlane swaps)
        unsigned int W[8];
        #pragma unroll
        for (int rp = 0; rp < 8; ++rp)
            W[rp] = cvt_pk_bf16(s[2*rp], s[2*rp + 1]);
        u32x4 bw[2];
        #pragma unroll
        for (int m = 0; m < 2; ++m)
            #pragma unroll
            for (int jp = 0; jp < 2; ++jp) {
                u32x2 sw = pl32swap(W[jp + 4*m], W[jp + 4*m + 2]);
                bw[m][jp]     = sw[0];
                bw[m][jp + 2] = sw[1];
            }
        // O^T += V^T * P'
        #pragma unroll
        for (int m = 0; m < 2; ++m) {
            o0 = __builtin_amdgcn_mfma_f32_32x32x16_bf16(vb[0][m], __builtin_bit_cast(bf16x8, bw[m]), o0, 0, 0, 0);
            o1 = __builtin_amdgcn_mfma_f32_32x32x16_bf16(vb[1][m], __builtin_bit_cast(bf16x8, bw[m]), o1, 0, 0, 0);
        }
        // prefetch V(t+2) (consumed ~1.5 tiles later)
        if (t + 2 <= chunk) {
            #pragma unroll
            for (int m = 0; m < 2; ++m) {
                vb[0][m] = *(const bf16x8*)&vp[lq*Tn        + s0 + 64 + m*16 + hi*8];
                vb[1][m] = *(const bf16x8*)&vp[(32 + lq)*Tn + s0 + 64 + m*16 + hi*8];
            }
        }
    };

    int t = 0;
    while (true) {
        tile(t, kbA, vbA);
        if (t == chunk) break;
        tile(t + 1, kbB, vbB);
        if (t + 1 == chunk) break;
        t += 2;
    }

    // epilogue: normalize, per-wave LDS transpose, coalesced 16B stores
    float inv_l = 1.0f / l_run;
    #pragma unroll
    for (int e = 0; e < 16; e += 2) {
        int dd = (e & 3) + 8*(e >> 2) + 4*hi;
        unsigned int wv0 = cvt_pk_bf16(o0[e]*inv_l, o0[e+1]*inv_l);
        *(unsigned int*)(myLds + ((lq*128 + dd*2)      ^ ((lq & 7) << 4))) = wv0;
        unsigned int wv1 = cvt_pk_bf16(o1[e]*inv_l, o1[e+1]*inv_l);
        *(unsigned int*)(myLds + ((lq*128 + 64 + dd*2) ^ ((lq & 7) << 4))) = wv1;
    }
    int q2 = l >> 1, hf = l & 1;
    #pragma unroll
    for (int o4 = 0; o4 < 4; ++o4) {
        u32x4 vr = *(u32x4*)(myLds + ((q2*128 + hf*64 + o4*16) ^ ((q2 & 7) << 4)));
        *(u32x4*)&op[(qw + q2)*Kn + hf*32 + o4*8] = vr;
    }
}

// ---------------- output projection: 16 rows/block, 4-way K-split + LDS reduce ------
__global__ __launch_bounds__(256) void proj_kernel(
    const unsigned short* __restrict__ attn, const unsigned short* __restrict__ wu_b,
    const float* __restrict__ bu, float* __restrict__ outp)
{
    __shared__ float red[4*16*66];
    const int r0 = blockIdx.x * 16;
    const int tid = threadIdx.x;
    const int w = tid >> 6, l = tid & 63;
    const int lr = l & 15, lh = l >> 4;
    f32x4 acc[4] = {};
    const int r = r0 + lr;
    const int bb = r >> 11, tt = r & 2047;
    #pragma unroll
    for (int ki = 0; ki < 4; ++ki) {
        int kk = w*4 + ki;
        int ch = kk*32 + lh*8;
        int hh = ch >> 6, dd = ch & 63;
        bf16x8 a = *(const bf16x8*)&attn[(size_t)((bb*Hn + hh)*Tn + tt)*Kn + dd];
        #pragma unroll
        for (int n = 0; n < 4; ++n) {
            bf16x8 bf = *(const bf16x8*)&wu_b[(n*16 + lr)*CHn + ch];
            acc[n] = __builtin_amdgcn_mfma_f32_16x16x32_bf16(a, bf, acc[n], 0, 0, 0);
        }
    }
    #pragma unroll
    for (int n = 0; n < 4; ++n)
        #pragma unroll
        for (int reg = 0; reg < 4; ++reg)
            red[w*1056 + (lh*4 + reg)*66 + n*16 + lr] = acc[n][reg];
    __syncthreads();
    #pragma unroll
    for (int it = 0; it < 4; ++it) {
        int idx = tid + it*256;
        int rl = idx >> 6, ko = idx & 63;
        float s = red[rl*66 + ko] + red[1056 + rl*66 + ko]
                + red[2112 + rl*66 + ko] + red[3168 + rl*66 + ko] + bu[ko];
        outp[(size_t)(r0 + rl)*Kn + ko] = s;
    }
}

extern "C" void kernel_launch(void* const* d_in, const int* in_sizes, int n_in,
                              void* d_out, int out_size, void* d_ws, size_t ws_size,
                              hipStream_t stream)
{
    const float* x  = (const float*)d_in[0];
    const float* wq = (const float*)d_in[1];
    const float* bq = (const float*)d_in[2];
    const float* wk = (const float*)d_in[3];
    const float* bk = (const float*)d_in[4];
    const float* wv = (const float*)d_in[5];
    const float* wu = (const float*)d_in[6];
    const float* bu = (const float*)d_in[7];
    float* outp = (float*)d_out;

    char* ws = (char*)d_ws;
    size_t off = 0;
    auto alloc = [&](size_t bytes) {
        char* p = ws + off;
        off = (off + bytes + 255) & ~(size_t)255;
        return p;
    };
    unsigned short* x_pad = (unsigned short*)alloc((size_t)Bn*TPADn*Kn*2);
    unsigned short* w2q  = (unsigned short*)alloc((size_t)KSn*CHn*Kn*2);
    unsigned short* w2k  = (unsigned short*)alloc((size_t)KSn*CHn*Kn*2);
    unsigned short* w2v  = (unsigned short*)alloc((size_t)KSn*CHn*Kn*2);
    unsigned short* wu_b = (unsigned short*)alloc((size_t)CHn*Kn*2);
    float*  bqs = (float*)alloc(CHn*4);
    float*  bks = (float*)alloc(CHn*4);
    unsigned short* q_s  = (unsigned short*)alloc((size_t)Bn*Hn*Tn*Kn*2);
    unsigned short* k_s  = (unsigned short*)alloc((size_t)Bn*Hn*Tn*Kn*2);
    unsigned short* v_t  = (unsigned short*)alloc((size_t)Bn*Hn*Tn*Kn*2);
    unsigned short* attn = (unsigned short*)alloc((size_t)Bn*Tn*CHn*2);

    prep_kernel<<<2048, 256, 0, stream>>>(x, wq, bq, wk, bk, wv, wu,
                                          x_pad, w2q, w2k, w2v, wu_b, bqs, bks);
    conv_v4<<<dim3(4, 8, 24), 256, 0, stream>>>(
        x_pad, w2q, w2k, w2v, bqs, bks, q_s, k_s, v_t);
    attn_kernel<<<1024, 256, 0, stream>>>(q_s, k_s, v_t, attn);
    proj_kernel<<<(Bn*Tn)/16, 256, 0, stream>>>(attn, wu_b, bu, outp);
}